// Round 10
// baseline (54.177 us; speedup 1.0000x reference)
//
#include <hip/hip_runtime.h>

#define P_TOT 30000
#define NPT   100
#define COUT  64

typedef __attribute__((ext_vector_type(2))) float f32x2;

static constexpr float VXf   = 0.16f;
static constexpr float VYf   = 0.16f;
static constexpr float XOFFf = 0.08f;            // VX/2 + 0.0
static constexpr float YOFFf = 0.08f - 39.68f;   // VY/2 + y_min
static constexpr float INV_M = 1.0f / 3000000.0f; // 1/(P*N)
static constexpr float NEGI  = -3.0e38f;

__device__ inline float wred(float v) {
#pragma unroll
  for (int d = 1; d < 64; d <<= 1) v += __shfl_xor(v, d);
  return v;
}

// (bf16(hi) << 16) | bf16(lo): lo = earlier point, hi = later point
__device__ inline unsigned pack_bf2(float lo, float hi) {
  return (__float_as_uint(hi) & 0xFFFF0000u) | (__float_as_uint(lo) >> 16);
}
// unpack one packed bf16 pair -> f32x2 {lo, hi}
__device__ inline f32x2 unpk(unsigned u) {
  f32x2 r;
  r.x = __uint_as_float(u << 16);
  r.y = __uint_as_float(u & 0xFFFF0000u);
  return r;
}

// K1: one pass over features, software-pipelined over pillars (r7 structure).
// Points staged in LDS as PAIR-TRANSPOSED bf16: pair m = uint4
//   {pack(x0,x1), pack(y0,y1), pack(z0,z1), pack(w0,w1)}  -> 16B per 2 points.
// This HALVES LDS broadcast return bytes vs f32 (the measured bottleneck).
// Inner loop: 1 ds_read_b128 per pair; unpack; packed-f32 math (2 pts/instr).
// Bias folded in closed form after the loop:
//   ymax = zmax + b ; Sum(y) = Sz + np*b ; Sum(y^2) = Sq + b*(2*Sz + np*b)
__global__ __launch_bounds__(256) void k1_pk(
    const float4* __restrict__ feat, const int* __restrict__ npts,
    const int* __restrict__ coords, const float* __restrict__ W,
    float* __restrict__ ymax, float* __restrict__ partials, int nb) {
  const int lane = threadIdx.x & 63;
  const int wv   = threadIdx.x >> 6;
  const int wave_id = blockIdx.x * 4 + wv;
  const int nwaves  = nb * 4;

  // per-channel weights, affine-folded: ce = (w0+w4+w7, w1+w5+w8, w2+w6, w3)
  float wr[9];
#pragma unroll
  for (int i = 0; i < 9; i++) wr[i] = W[lane * 9 + i];
  const float ce0 = wr[0] + wr[4] + wr[7];
  const float ce1 = wr[1] + wr[5] + wr[8];
  const float ce2 = wr[2] + wr[6];
  const float ce3 = wr[3];
  const f32x2 cex2 = {ce0, ce0};
  const f32x2 cey2 = {ce1, ce1};
  const f32x2 cez2 = {ce2, ce2};
  const f32x2 cew2 = {ce3, ce3};

  float sum = 0.f, sumsq = 0.f;
  __shared__ __align__(16) uint4 sbuf[4][50];   // 50 bf16 pairs per wave

  const bool even = (lane & 1) == 0;

  // prologue: load pillar wave_id
  int p = wave_id;
  float4 a0 = make_float4(0.f, 0.f, 0.f, 0.f), a1 = a0;
  int np = 1, cx = 0, cy = 0;
  if (p < P_TOT) {
    const float4* fp = feat + (size_t)p * NPT;
    a0 = fp[lane];
    if (lane < 36) a1 = fp[lane + 64];
    np = npts[p];
    cx = coords[p * 4 + 3];
    cy = coords[p * 4 + 2];
  }

  while (p < P_TOT) {
    // prefetch next pillar (hides HBM latency under this pillar's compute)
    const int pn = p + nwaves;
    float4 b0 = make_float4(0.f, 0.f, 0.f, 0.f), b1 = b0;
    int npn = 1, cxn = 0, cyn = 0;
    if (pn < P_TOT) {
      const float4* fpn = feat + (size_t)pn * NPT;
      b0 = fpn[lane];
      if (lane < 36) b1 = fpn[lane + 64];
      npn = npts[pn];
      cxn = coords[pn * 4 + 3];
      cyn = coords[pn * 4 + 2];
    }

    // stage: pair-transpose exchange + bf16 pack. Even lane sends (z,w) and
    // receives neighbor's (x,y); it writes the {xx,yy} half of the pair slot,
    // odd lane writes {zz,ww}. uint2 index = 2*pair + parity = lane. 8B/lane.
    uint2* sb2 = (uint2*)&sbuf[wv][0];
    {
      const float r0 = __shfl_xor(even ? a0.z : a0.x, 1);
      const float r1 = __shfl_xor(even ? a0.w : a0.y, 1);
      sb2[lane] = even ? make_uint2(pack_bf2(a0.x, r0), pack_bf2(a0.y, r1))
                       : make_uint2(pack_bf2(r0, a0.z), pack_bf2(r1, a0.w));
    }
    if (lane < 36) {
      const float r0 = __shfl_xor(even ? a1.z : a1.x, 1);
      const float r1 = __shfl_xor(even ? a1.w : a1.y, 1);
      sb2[lane + 64] = even ? make_uint2(pack_bf2(a1.x, r0), pack_bf2(a1.y, r1))
                            : make_uint2(pack_bf2(r0, a1.z), pack_bf2(r1, a1.w));
    }
    asm volatile("s_waitcnt lgkmcnt(0)" ::: "memory");

    const uint4* base = sbuf[wv];
    f32x2 zmA = {NEGI, NEGI}, zmB = {NEGI, NEGI};
    f32x2 zsA = {0.f, 0.f}, zsB = {0.f, 0.f};
    f32x2 zqA = {0.f, 0.f}, zqB = {0.f, 0.f};

    const int Pp = np >> 1;   // full pairs
    int m = 0;
    for (; m + 2 <= Pp; m += 2) {
      const uint4 U = base[m];
      const uint4 V = base[m + 1];
      f32x2 z1 = unpk(U.x) * cex2;
      f32x2 z2 = unpk(V.x) * cex2;
      z1 += unpk(U.y) * cey2;
      z2 += unpk(V.y) * cey2;
      z1 += unpk(U.z) * cez2;
      z2 += unpk(V.z) * cez2;
      z1 += unpk(U.w) * cew2;
      z2 += unpk(V.w) * cew2;
      zmA = __builtin_elementwise_max(zmA, z1);
      zmB = __builtin_elementwise_max(zmB, z2);
      zsA += z1;
      zsB += z2;
      zqA += z1 * z1;
      zqB += z2 * z2;
    }
    if (m < Pp) {
      const uint4 U = base[m];
      f32x2 z1 = unpk(U.x) * cex2;
      z1 += unpk(U.y) * cey2;
      z1 += unpk(U.z) * cez2;
      z1 += unpk(U.w) * cew2;
      zmA = __builtin_elementwise_max(zmA, z1);
      zsA += z1;
      zqA += z1 * z1;
    }
    if (np & 1) {
      // last point np-1 (even position) = lo halves of pair slot Pp
      const uint4 U = base[Pp];
      float zx = __uint_as_float(U.x << 16) * ce0;
      zx = fmaf(__uint_as_float(U.y << 16), ce1, zx);
      zx = fmaf(__uint_as_float(U.z << 16), ce2, zx);
      zx = fmaf(__uint_as_float(U.w << 16), ce3, zx);
      zmA.x = fmaxf(zmA.x, zx);
      zsA.x += zx;
      zqA.x = fmaf(zx, zx, zqA.x);
    }

    // cross-lane xyz sums AFTER the z-loop, from f32 registers
    // (reference: sum over ALL 100 rows / num_points)
    const float sax = wred(a0.x + a1.x);
    const float say = wred(a0.y + a1.y);
    const float saz = wred(a0.z + a1.z);
    const float inv = 1.f / (float)np;
    const float cxc = (float)cx * VXf + XOFFf;
    const float cyc = (float)cy * VYf + YOFFf;
    float b = wr[4] * (sax * inv);
    b = fmaf(wr[5], say * inv, b);
    b = fmaf(wr[6], saz * inv, b);
    b = fmaf(wr[7], cxc, b);
    b = fmaf(wr[8], cyc, b);
    b = -b;

    const float zm = fmaxf(fmaxf(zmA.x, zmA.y), fmaxf(zmB.x, zmB.y));
    const float zs = (zsA.x + zsA.y) + (zsB.x + zsB.y);
    const float zq = (zqA.x + zqA.y) + (zqB.x + zqB.y);
    const float npf = (float)np;
    ymax[p * COUT + lane] = zm + b;
    sum   += zs + npf * b;
    sumsq += zq + b * fmaf(npf, b, 2.f * zs);

    p = pn;
    a0 = b0; a1 = b1; np = npn; cx = cxn; cy = cyn;
  }

  __syncthreads();
  __shared__ float rs[4][64], rq[4][64];
  rs[wv][lane] = sum;
  rq[wv][lane] = sumsq;
  __syncthreads();
  const int t = threadIdx.x;
  if (t < 128) {
    const int c = t & 63;
    float v;
    if (t < 64) v = rs[0][c] + rs[1][c] + rs[2][c] + rs[3][c];
    else        v = rq[0][c] + rq[1][c] + rq[2][c] + rq[3][c];
    partials[(size_t)blockIdx.x * 128 + t] = v;   // coalesced, block-major
  }
}

// K2: 128 blocks (one per moment), 256 threads each -> TLP hides latency
__global__ __launch_bounds__(256) void k2_reduce(
    const float* __restrict__ partials, int nb, float* __restrict__ S) {
  const int m = blockIdx.x;
  float s = 0.f;
  for (int b = threadIdx.x; b < nb; b += 256) s += partials[(size_t)b * 128 + m];
  s = wred(s);
  __shared__ float t4[4];
  if ((threadIdx.x & 63) == 0) t4[threadIdx.x >> 6] = s;
  __syncthreads();
  if (threadIdx.x == 0) S[m] = t4[0] + t4[1] + t4[2] + t4[3];
}

// K3: finish in place on d_out. Each thread derives its channel's scale/shift
// from S (gamma==1 => scale>0, so max commutes with the BN affine).
__global__ __launch_bounds__(256) void k3_finish(
    const int* __restrict__ npts, const float* __restrict__ S,
    const float* __restrict__ gamma, const float* __restrict__ beta,
    float* __restrict__ out) {
  const int c  = threadIdx.x & 63;
  const int wv = threadIdx.x >> 6;
  const int p  = blockIdx.x * 4 + wv;   // 7500*4 == 30000

  const float mean  = S[c] * INV_M;
  const float var   = S[64 + c] * INV_M - mean * mean;
  const float scale = gamma[c] * rsqrtf(var + 0.001f);
  const float shift = beta[c] - mean * scale;

  const int np = npts[p];
  float v = fmaf(scale, out[p * COUT + c], shift);
  if (np < NPT) v = fmaxf(v, shift);   // padded positions contribute relu(shift)
  out[p * COUT + c] = fmaxf(v, 0.f);
}

extern "C" void kernel_launch(void* const* d_in, const int* in_sizes, int n_in,
                              void* d_out, int out_size, void* d_ws, size_t ws_size,
                              hipStream_t stream) {
  const float4* feat  = (const float4*)d_in[0];
  const int*   npts   = (const int*)d_in[1];
  const int*   coords = (const int*)d_in[2];
  const float* W      = (const float*)d_in[3];
  const float* gamma  = (const float*)d_in[4];
  const float* beta   = (const float*)d_in[5];
  float* out = (float*)d_out;

  int nb = 512;
  if (ws_size >= (size_t)(128 + 2048 * 128) * 4) nb = 2048;
  else if (ws_size >= (size_t)(128 + 1024 * 128) * 4) nb = 1024;

  float* S        = (float*)d_ws;   // 128 floats
  float* partials = S + 128;        // nb*128 floats, block-major

  k1_pk<<<nb, 256, 0, stream>>>(feat, npts, coords, W, out, partials, nb);
  k2_reduce<<<128, 256, 0, stream>>>(partials, nb, S);
  k3_finish<<<P_TOT / 4, 256, 0, stream>>>(npts, S, gamma, beta, out);
}

// Round 11
// 41.663 us; speedup vs baseline: 1.3004x; 1.3004x over previous
//
#include <hip/hip_runtime.h>

#define P_TOT 30000
#define NPT   100
#define COUT  64

typedef __attribute__((ext_vector_type(8)))  short bf16x8;
typedef __attribute__((ext_vector_type(16))) float f32x16;

static constexpr float VXf   = 0.16f;
static constexpr float VYf   = 0.16f;
static constexpr float XOFFf = 0.08f;            // VX/2 + 0.0
static constexpr float YOFFf = 0.08f - 39.68f;   // VY/2 + y_min
static constexpr float INV_M = 1.0f / 3000000.0f; // 1/(P*N)
static constexpr float NEGI  = -3.0e38f;

__device__ inline float wred(float v) {
#pragma unroll
  for (int d = 1; d < 64; d <<= 1) v += __shfl_xor(v, d);
  return v;
}

// (bf16(hi) << 16) | bf16(lo)
__device__ inline unsigned pack_bf2(float lo, float hi) {
  return (__float_as_uint(hi) & 0xFFFF0000u) | (__float_as_uint(lo) >> 16);
}

union AF { bf16x8 v; unsigned u[4]; };

__device__ inline void fold_full(const f32x16& c, float& zm, float& zs, float& zq) {
#pragma unroll
  for (int r = 0; r < 16; ++r) {
    const float cv = c[r];
    zm = fmaxf(zm, cv);
    zs += cv;
    zq = fmaf(cv, cv, zq);
  }
}

__device__ inline void fold_mask(const f32x16& c, int thresh,
                                 float& zm, float& zs, float& zq) {
#pragma unroll
  for (int r = 0; r < 16; ++r) {
    const int ro = (r & 3) + 8 * (r >> 2);   // compile-time row offset
    const float cv = c[r];
    zm = fmaxf(zm, (ro < thresh) ? cv : NEGI);  // exclude zero-staged pad rows
    zs += cv;                                    // pad rows are exactly 0
    zq = fmaf(cv, cv, zq);
  }
}

// K1: one pass over features, r7 prefetch structure, z via mfma_32x32x16_bf16.
// Points staged bf16 in LDS: slot s (8B) = {pack(x,y), pack(z,w)} of point s;
// invalid points staged 0 (contribute 0 to sums; excluded from max by mask).
// A-frag: lanes<32 hold row lane&31, real k=0..3 in slots {u0,u1}; lanes>=32
// and u2/u3 zero (K zero-pad => any consistent HW k-mapping gives z = ce.q).
// B-frag n: lane holds channel n*32+(lane&31)'s {ce0..3} in the SAME slots.
// C layout (m74/m101-verified): col = lane&31, row = (r&3)+8*(r>>2)+4*(lane>>5).
// Per-channel epilogue identical to r7:
//   ymax = zmax + b ; sum += Sz + np*b ; sumsq += Sq + b*(2*Sz + np*b)
__global__ __launch_bounds__(256) void k1_mfma(
    const float4* __restrict__ feat, const int* __restrict__ npts,
    const int* __restrict__ coords, const float* __restrict__ W,
    float* __restrict__ ymax, float* __restrict__ partials, int nb) {
  const int lane = threadIdx.x & 63;
  const int wv   = threadIdx.x >> 6;
  const int wave_id = blockIdx.x * 4 + wv;
  const int nwaves  = nb * 4;
  const int rbase   = (lane >> 5) * 4;

  // per-channel weights, affine-folded: ce = (w0+w4+w7, w1+w5+w8, w2+w6, w3)
  float wr[9];
#pragma unroll
  for (int i = 0; i < 9; i++) wr[i] = W[lane * 9 + i];
  const float ce0 = wr[0] + wr[4] + wr[7];
  const float ce1 = wr[1] + wr[5] + wr[8];
  const float ce2 = wr[2] + wr[6];
  const float ce3 = wr[3];

  // B fragments: lane -> channel n*32+(lane&31), packed in slots u0,u1
  AF bf0, bf1;
  {
    const unsigned p01 = pack_bf2(ce0, ce1);
    const unsigned p23 = pack_bf2(ce2, ce3);
    const int s0 = lane & 31, s1 = 32 + (lane & 31);
    unsigned b0a = (unsigned)__shfl((int)p01, s0);
    unsigned b0b = (unsigned)__shfl((int)p23, s0);
    unsigned b1a = (unsigned)__shfl((int)p01, s1);
    unsigned b1b = (unsigned)__shfl((int)p23, s1);
    if (lane >= 32) { b0a = b0b = b1a = b1b = 0; }
    bf0.u[0] = b0a; bf0.u[1] = b0b; bf0.u[2] = 0; bf0.u[3] = 0;
    bf1.u[0] = b1a; bf1.u[1] = b1b; bf1.u[2] = 0; bf1.u[3] = 0;
  }

  __shared__ uint2 sbuf[4][128];   // 8B slot per point, 128 slots per wave
  // slots 112..127 never staged -> zero once (tile 3 rows 100..127)
  for (int i = threadIdx.x; i < 4 * 16; i += 256)
    sbuf[i >> 4][112 + (i & 15)] = make_uint2(0u, 0u);
  __syncthreads();

  const f32x16 z16 = {0.f};
  float sum = 0.f, sumsq = 0.f;

  // prologue: load pillar wave_id (r7 prefetch structure)
  int p = wave_id;
  float4 a0 = make_float4(0.f, 0.f, 0.f, 0.f), a1 = a0;
  int np = 1, cx = 0, cy = 0;
  if (p < P_TOT) {
    const float4* fp = feat + (size_t)p * NPT;
    a0 = fp[lane];
    if (lane < 36) a1 = fp[lane + 64];
    np = npts[p];
    cx = coords[p * 4 + 3];
    cy = coords[p * 4 + 2];
  }

  while (p < P_TOT) {
    const int pn = p + nwaves;
    float4 b0 = make_float4(0.f, 0.f, 0.f, 0.f), b1 = b0;
    int npn = 1, cxn = 0, cyn = 0;
    if (pn < P_TOT) {
      const float4* fpn = feat + (size_t)pn * NPT;
      b0 = fpn[lane];
      if (lane < 36) b1 = fpn[lane + 64];
      npn = npts[pn];
      cxn = coords[pn * 4 + 3];
      cyn = coords[pn * 4 + 2];
    }

    // stage masked points as bf16 (8B per point)
    {
      const bool v0 = lane < np;
      const float m0x = v0 ? a0.x : 0.f, m0y = v0 ? a0.y : 0.f;
      const float m0z = v0 ? a0.z : 0.f, m0w = v0 ? a0.w : 0.f;
      sbuf[wv][lane] = make_uint2(pack_bf2(m0x, m0y), pack_bf2(m0z, m0w));
      if (lane < 48) {
        const bool v1 = lane + 64 < np;
        const float m1x = v1 ? a1.x : 0.f, m1y = v1 ? a1.y : 0.f;
        const float m1z = v1 ? a1.z : 0.f, m1w = v1 ? a1.w : 0.f;
        sbuf[wv][lane + 64] = make_uint2(pack_bf2(m1x, m1y), pack_bf2(m1z, m1w));
      }
    }
    asm volatile("s_waitcnt lgkmcnt(0)" ::: "memory");

    // z-loop: T tiles of 32 points, 2 MFMAs each (channel halves)
    float zm0 = NEGI, zm1 = NEGI;
    float zs0 = 0.f, zs1 = 0.f, zq0 = 0.f, zq1 = 0.f;
    const int T = (np + 31) >> 5;
    for (int t = 0; t < T; ++t) {
      uint2 s = sbuf[wv][(lane & 31) + 32 * t];
      if (lane >= 32) s = make_uint2(0u, 0u);   // k-group 1 = zero pad
      AF af;
      af.u[0] = s.x; af.u[1] = s.y; af.u[2] = 0; af.u[3] = 0;
      f32x16 c0 = __builtin_amdgcn_mfma_f32_32x32x16_bf16(af.v, bf0.v, z16, 0, 0, 0);
      f32x16 c1 = __builtin_amdgcn_mfma_f32_32x32x16_bf16(af.v, bf1.v, z16, 0, 0, 0);
      if (32 * t + 32 <= np) {
        fold_full(c0, zm0, zs0, zq0);
        fold_full(c1, zm1, zs1, zq1);
      } else {
        const int thresh = np - 32 * t - rbase;
        fold_mask(c0, thresh, zm0, zs0, zq0);
        fold_mask(c1, thresh, zm1, zs1, zq1);
      }
    }

    // cross-lane xyz sums (reference: sum over ALL 100 rows / num_points)
    const float sax = wred(a0.x + a1.x);
    const float say = wred(a0.y + a1.y);
    const float saz = wred(a0.z + a1.z);
    const float inv = 1.f / (float)np;
    const float cxc = (float)cx * VXf + XOFFf;
    const float cyc = (float)cy * VYf + YOFFf;
    float b = wr[4] * (sax * inv);
    b = fmaf(wr[5], say * inv, b);
    b = fmaf(wr[6], saz * inv, b);
    b = fmaf(wr[7], cxc, b);
    b = fmaf(wr[8], cyc, b);
    b = -b;

    // combine row-halves (lane>>5), then pick this lane's channel half
    zm0 = fmaxf(zm0, __shfl_xor(zm0, 32));
    zm1 = fmaxf(zm1, __shfl_xor(zm1, 32));
    zs0 += __shfl_xor(zs0, 32);
    zs1 += __shfl_xor(zs1, 32);
    zq0 += __shfl_xor(zq0, 32);
    zq1 += __shfl_xor(zq1, 32);
    const float zm = (lane < 32) ? zm0 : zm1;   // channel = lane
    const float zs = (lane < 32) ? zs0 : zs1;
    const float zq = (lane < 32) ? zq0 : zq1;

    const float npf = (float)np;
    ymax[p * COUT + lane] = zm + b;
    sum   += zs + npf * b;
    sumsq += zq + b * fmaf(npf, b, 2.f * zs);

    p = pn;
    a0 = b0; a1 = b1; np = npn; cx = cxn; cy = cyn;
  }

  __syncthreads();
  __shared__ float rs[4][64], rq[4][64];
  rs[wv][lane] = sum;
  rq[wv][lane] = sumsq;
  __syncthreads();
  const int t = threadIdx.x;
  if (t < 128) {
    const int c = t & 63;
    float v;
    if (t < 64) v = rs[0][c] + rs[1][c] + rs[2][c] + rs[3][c];
    else        v = rq[0][c] + rq[1][c] + rq[2][c] + rq[3][c];
    partials[(size_t)blockIdx.x * 128 + t] = v;   // coalesced, block-major
  }
}

// K2: 128 blocks (one per moment), 256 threads each -> TLP hides latency
__global__ __launch_bounds__(256) void k2_reduce(
    const float* __restrict__ partials, int nb, float* __restrict__ S) {
  const int m = blockIdx.x;
  float s = 0.f;
  for (int b = threadIdx.x; b < nb; b += 256) s += partials[(size_t)b * 128 + m];
  s = wred(s);
  __shared__ float t4[4];
  if ((threadIdx.x & 63) == 0) t4[threadIdx.x >> 6] = s;
  __syncthreads();
  if (threadIdx.x == 0) S[m] = t4[0] + t4[1] + t4[2] + t4[3];
}

// K3: finish in place on d_out. gamma==1 => scale>0, so max commutes with BN.
__global__ __launch_bounds__(256) void k3_finish(
    const int* __restrict__ npts, const float* __restrict__ S,
    const float* __restrict__ gamma, const float* __restrict__ beta,
    float* __restrict__ out) {
  const int c  = threadIdx.x & 63;
  const int wv = threadIdx.x >> 6;
  const int p  = blockIdx.x * 4 + wv;   // 7500*4 == 30000

  const float mean  = S[c] * INV_M;
  const float var   = S[64 + c] * INV_M - mean * mean;
  const float scale = gamma[c] * rsqrtf(var + 0.001f);
  const float shift = beta[c] - mean * scale;

  const int np = npts[p];
  float v = fmaf(scale, out[p * COUT + c], shift);
  if (np < NPT) v = fmaxf(v, shift);   // padded positions contribute relu(shift)
  out[p * COUT + c] = fmaxf(v, 0.f);
}

extern "C" void kernel_launch(void* const* d_in, const int* in_sizes, int n_in,
                              void* d_out, int out_size, void* d_ws, size_t ws_size,
                              hipStream_t stream) {
  const float4* feat  = (const float4*)d_in[0];
  const int*   npts   = (const int*)d_in[1];
  const int*   coords = (const int*)d_in[2];
  const float* W      = (const float*)d_in[3];
  const float* gamma  = (const float*)d_in[4];
  const float* beta   = (const float*)d_in[5];
  float* out = (float*)d_out;

  int nb = 512;
  if (ws_size >= (size_t)(128 + 2048 * 128) * 4) nb = 2048;
  else if (ws_size >= (size_t)(128 + 1024 * 128) * 4) nb = 1024;

  float* S        = (float*)d_ws;   // 128 floats
  float* partials = S + 128;        // nb*128 floats, block-major

  k1_mfma<<<nb, 256, 0, stream>>>(feat, npts, coords, W, out, partials, nb);
  k2_reduce<<<128, 256, 0, stream>>>(partials, nb, S);
  k3_finish<<<P_TOT / 4, 256, 0, stream>>>(npts, S, gamma, beta, out);
}